// Round 8
// baseline (163.182 us; speedup 1.0000x reference)
//
#include <hip/hip_runtime.h>

#define RPW 4            // rows per wave
#define WAVES 2          // waves per block
#define RPB (RPW * WAVES)   // 8 rows per block
#define NM 14               // Taylor degree (terms 0..14)

using short8 = __attribute__((ext_vector_type(8))) short;
using f32x4  = __attribute__((ext_vector_type(4))) float;

#define LOG2E 1.4426950408889634f

static __device__ __forceinline__ float ex2(float x) { return __builtin_amdgcn_exp2f(x); }
static __device__ __forceinline__ float rcpf_(float x) { return __builtin_amdgcn_rcpf(x); }
static __device__ __forceinline__ float silu_(float x) {
    return x * rcpf_(1.0f + ex2(-x * LOG2E));
}
static __device__ __forceinline__ unsigned short bfhi(float x) {          // truncate
    return (unsigned short)(__float_as_uint(x) >> 16);
}
static __device__ __forceinline__ unsigned short bfrn(float x) {          // round-nearest
    unsigned u = __float_as_uint(x);
    return (unsigned short)((u + 0x7fffu + ((u >> 16) & 1u)) >> 16);
}
static __device__ __forceinline__ float bf2f(unsigned short h) {
    return __uint_as_float(((unsigned)h) << 16);
}

// ---- DPP 16-lane rotation-sum: VALU pipe, zero LDS traffic ------------------
template <int CTRL>
static __device__ __forceinline__ float dpp_rot(float v) {
    return __uint_as_float(
        __builtin_amdgcn_update_dpp(0u, __float_as_uint(v), CTRL, 0xF, 0xF, true));
}
static __device__ __forceinline__ float rsum16(float v) {
    v += dpp_rot<0x128>(v);   // row_ror:8
    v += dpp_rot<0x124>(v);   // row_ror:4
    v += dpp_rot<0x122>(v);   // row_ror:2
    v += dpp_rot<0x121>(v);   // row_ror:1
    return v;
}

__constant__ float c_invfact[15] = {
    1.f, 1.f, 0.5f, 1.f/6, 1.f/24, 1.f/120, 1.f/720, 1.f/5040, 1.f/40320,
    1.f/362880, 1.f/3628800, 1.f/39916800, 1.f/479001600,
    1.f/6227020800.f, 1.f/87178291200.f};

// ---------------- weight prep in d_ws ---------------------------------------
template <int O, int I>
__device__ __forceinline__ void tr(const float* __restrict__ s, float* __restrict__ d,
                                   int t0, int stride) {
    for (int idx = t0; idx < O * I; idx += stride) {
        int o = idx / I, in = idx - o * I;
        d[in * O + o] = s[idx];
    }
}
template <int N>
__device__ __forceinline__ void cvt(const float* __restrict__ s,
                                    unsigned short* __restrict__ hi,
                                    unsigned short* __restrict__ lo,
                                    int t0, int stride) {
    for (int i = t0; i < N; i += stride) {
        float a = s[i];
        unsigned short h = bfhi(a);
        float r = a - bf2f(h);
        hi[i] = h;
        lo[i] = bfhi(r);
    }
}

__global__ void tweights(const float* __restrict__ s0, const float* __restrict__ s1,
                         const float* __restrict__ s2, const float* __restrict__ s3,
                         const float* __restrict__ s4, const float* __restrict__ s5,
                         const float* __restrict__ s6, const float* __restrict__ s7,
                         const float* __restrict__ s8, float* __restrict__ ws) {
    const int stride = gridDim.x * blockDim.x;
    const int t0 = blockIdx.x * blockDim.x + threadIdx.x;
    tr<128, 12>(s0, ws + 0, t0, stride);                       // WinT fp32 [12][128]
    unsigned short* u4 = (unsigned short*)(ws + 1536);
    cvt<128 * 128>(s1, u4 + 0,     u4 + 16384, t0, stride);    // Aq4 hi/lo [o][in]
    cvt<128 * 128>(s2, u4 + 32768, u4 + 49152, t0, stride);    // Ak4
    cvt<128 * 128>(s3, u4 + 65536, u4 + 81920, t0, stride);    // Av4
    unsigned short* wh = (unsigned short*)(ws + 50688);
    cvt<64 * 128>(s4, wh + 0, wh + 8192, t0, stride);          // Wh hi/lo [64][128]
    unsigned short* u7 = (unsigned short*)(ws + 58880);
    cvt<64 * 64>(s5, u7 + 0,     u7 + 4096,  t0, stride);      // Aq7
    cvt<64 * 64>(s6, u7 + 8192,  u7 + 12288, t0, stride);      // Ak7
    cvt<64 * 64>(s7, u7 + 16384, u7 + 20480, t0, stride);      // Av7
    tr<25, 64>(s8, ws + 71168, t0, stride);                    // WoutT fp32 [64][25]
}

// ---------------- fused per-row network (8 rows / 2 waves per block) --------
__global__ __launch_bounds__(128, 4) void fused_net(
    const float* __restrict__ x, const float* __restrict__ ws,
    const float* __restrict__ b_in,
    const float* __restrict__ Bq4, const float* __restrict__ Bk4, const float* __restrict__ Bv4,
    const float* __restrict__ b_h,
    const float* __restrict__ Bq7, const float* __restrict__ Bk7, const float* __restrict__ Bv7,
    const float* __restrict__ b_out,
    float* __restrict__ out) {
    __shared__ __align__(16) unsigned short hAhi[8][136], hAlo[8][136];
    __shared__ __align__(16) unsigned short h2hi[8][80],  h2lo[8][80];
    __shared__ __align__(16) float sQ[8][132];               // q fp32
    __shared__ __align__(16) unsigned short sKVb[8][132][2]; // (k,v) bf16 packed
    __shared__ __align__(16) float h3T[WAVES][64][RPW];      // attn7 out transposed
    __shared__ __align__(16) float sXT[WAVES][12][RPW];
    __shared__ __align__(16) float sY[WAVES][RPW][26];

    const int tid = threadIdx.x;
    const int w = tid >> 6;
    const int l = tid & 63;
    const int row0 = blockIdx.x * RPB + w * RPW;
    const int m16 = l & 15, quad = l >> 4;
    const int g = l & 15, r = l >> 4;      // attention mapping: 16 lanes per row
    const int R = w * RPW + r;             // block-row this lane reduces/evaluates

    const float* WinT  = ws + 0;      // [12][128] fp32
    const float* WoutT = ws + 71168;  // [64][25]  fp32
    const unsigned short* u4 = (const unsigned short*)(ws + 1536);

    // P0: stage x transposed (wave-private; rows w*4..w*4+3)
    if (l < 12 * RPW) {
        float v = x[row0 * 12 + l];
        int rr = l / 12, in = l - rr * 12;
        sXT[w][in][rr] = v;
    }

    // prefetch P2 tile-0 B-fragments (no deps; hides under P0 wait + P1 VALU)
    short8 p2bh[4], p2bl[4];
    {
        const int nt = w * 12;
        const int mat = nt >> 3;
        const int n = (nt & 7) * 16 + m16;
        const unsigned short* Bh = u4 + mat * 32768 + n * 128;
        const unsigned short* Bl = Bh + 16384;
        #pragma unroll
        for (int kt = 0; kt < 4; kt++) {
            p2bh[kt] = *(const short8*)&Bh[kt * 32 + quad * 8];
            p2bl[kt] = *(const short8*)&Bl[kt * 32 + quad * 8];
        }
    }

    // P1: h = silu(x @ Win^T + b_in); lane owns cols 2l,2l+1 of wave's 4 rows
    {
        float2 bb = *(const float2*)&b_in[2 * l];
        float a0[RPW], a1[RPW];
        #pragma unroll
        for (int rr = 0; rr < RPW; rr++) { a0[rr] = bb.x; a1[rr] = bb.y; }
        #pragma unroll
        for (int in = 0; in < 12; in++) {
            float2 wv = *(const float2*)&WinT[in * 128 + 2 * l];
            float4 xr = *(const float4*)&sXT[w][in][0];
            a0[0] = fmaf(xr.x, wv.x, a0[0]); a1[0] = fmaf(xr.x, wv.y, a1[0]);
            a0[1] = fmaf(xr.y, wv.x, a0[1]); a1[1] = fmaf(xr.y, wv.y, a1[1]);
            a0[2] = fmaf(xr.z, wv.x, a0[2]); a1[2] = fmaf(xr.z, wv.y, a1[2]);
            a0[3] = fmaf(xr.w, wv.x, a0[3]); a1[3] = fmaf(xr.w, wv.y, a1[3]);
        }
        #pragma unroll
        for (int rr = 0; rr < RPW; rr++) {
            float h0 = silu_(a0[rr]), h1 = silu_(a1[rr]);
            unsigned short h0h = bfhi(h0), h1h = bfhi(h1);
            float r0 = h0 - bf2f(h0h), r1 = h1 - bf2f(h1h);
            *(unsigned*)&hAhi[w * 4 + rr][2 * l] = (unsigned)h0h | ((unsigned)h1h << 16);
            *(unsigned*)&hAlo[w * 4 + rr][2 * l] = (unsigned)bfhi(r0) | ((unsigned)bfhi(r1) << 16);
        }
    }
    __syncthreads();

    // P2: qkv4 via MFMA bf16x3. M=16 (8 rows dup), K=128, N=384. wave w: 12 tiles.
    {
        short8 Ah[4], Al[4];
        #pragma unroll
        for (int kt = 0; kt < 4; kt++) {
            Ah[kt] = *(const short8*)&hAhi[m16 & 7][kt * 32 + quad * 8];
            Al[kt] = *(const short8*)&hAlo[m16 & 7][kt * 32 + quad * 8];
        }
        #pragma unroll 4
        for (int t = 0; t < 12; t++) {
            const int nt = w * 12 + t;
            const int mat = nt >> 3;           // 0=q,1=k,2=v (wave-uniform)
            const int n = (nt & 7) * 16 + m16;
            const float* bp = (mat == 0) ? Bq4 : (mat == 1) ? Bk4 : Bv4;
            float b = bp[n];
            f32x4 acc0 = {b, b, b, b};
            f32x4 acc1 = {0.f, 0.f, 0.f, 0.f};
            const unsigned short* Bh = u4 + mat * 32768 + n * 128;
            const unsigned short* Bl = Bh + 16384;
            short8 bh[4], bl[4];
            if (t == 0) {
                #pragma unroll
                for (int kt = 0; kt < 4; kt++) { bh[kt] = p2bh[kt]; bl[kt] = p2bl[kt]; }
            } else {
                #pragma unroll
                for (int kt = 0; kt < 4; kt++) {
                    bh[kt] = *(const short8*)&Bh[kt * 32 + quad * 8];
                    bl[kt] = *(const short8*)&Bl[kt * 32 + quad * 8];
                }
            }
            #pragma unroll
            for (int kt = 0; kt < 4; kt++) {
                if (kt & 1) {
                    acc1 = __builtin_amdgcn_mfma_f32_16x16x32_bf16(Ah[kt], bh[kt], acc1, 0, 0, 0);
                    acc1 = __builtin_amdgcn_mfma_f32_16x16x32_bf16(Ah[kt], bl[kt], acc1, 0, 0, 0);
                    acc1 = __builtin_amdgcn_mfma_f32_16x16x32_bf16(Al[kt], bh[kt], acc1, 0, 0, 0);
                } else {
                    acc0 = __builtin_amdgcn_mfma_f32_16x16x32_bf16(Ah[kt], bh[kt], acc0, 0, 0, 0);
                    acc0 = __builtin_amdgcn_mfma_f32_16x16x32_bf16(Ah[kt], bl[kt], acc0, 0, 0, 0);
                    acc0 = __builtin_amdgcn_mfma_f32_16x16x32_bf16(Al[kt], bh[kt], acc0, 0, 0, 0);
                }
            }
            if (quad < 2) {
                #pragma unroll
                for (int reg = 0; reg < 4; reg++) {
                    int row = quad * 4 + reg;
                    float val = silu_(acc0[reg] + acc1[reg]);
                    if (mat == 0)      sQ[row][n] = val;
                    else if (mat == 1) sKVb[row][n][0] = bfrn(val);
                    else               sKVb[row][n][1] = bfrn(val);
                }
            }
        }
    }
    __syncthreads();

    // P3: attention over 128 via Taylor moments. 16 lanes per row.
    {
        // prefetch P4 tile-0 B-fragments (hidden under P3's long VALU stretch)
        short8 p4bh[4], p4bl[4];
        const unsigned short* whh = (const unsigned short*)(ws + 50688);
        const unsigned short* whl = whh + 8192;
        {
            const int n4 = (w * 2) * 16 + m16;
            #pragma unroll
            for (int kt = 0; kt < 4; kt++) {
                p4bh[kt] = *(const short8*)&whh[n4 * 128 + kt * 32 + quad * 8];
                p4bl[kt] = *(const short8*)&whl[n4 * 128 + kt * 32 + quad * 8];
            }
        }
        float dmom[NM];       // delta_1..14
        float nmom[NM + 1];   // nu_0..14
        #pragma unroll
        for (int m = 0; m < NM; m++) dmom[m] = 0.f;
        #pragma unroll
        for (int m = 0; m <= NM; m++) nmom[m] = 0.f;
        uint4 u0 = *(const uint4*)&sKVb[R][g * 8][0];
        uint4 u1 = *(const uint4*)&sKVb[R][g * 8 + 4][0];
        unsigned us[8] = {u0.x, u0.y, u0.z, u0.w, u1.x, u1.y, u1.z, u1.w};
        #pragma unroll
        for (int jj = 0; jj < 8; jj++) {
            unsigned u = us[jj];
            float kf = __uint_as_float(u << 16);
            float vf = __uint_as_float(u & 0xffff0000u);
            nmom[0] += vf;
            float p = kf;
            dmom[0] += p; nmom[1] = fmaf(vf, p, nmom[1]);
            #pragma unroll
            for (int m = 1; m < NM; m++) {
                p *= kf;
                dmom[m] += p;
                nmom[m + 1] = fmaf(vf, p, nmom[m + 1]);
            }
        }
        #pragma unroll
        for (int m = 0; m < NM; m++) dmom[m] = rsum16(dmom[m]);
        #pragma unroll
        for (int m = 0; m <= NM; m++) nmom[m] = rsum16(nmom[m]);
        float cd[NM + 1], cn[NM + 1];
        cd[0] = 128.f; cn[0] = nmom[0];
        #pragma unroll
        for (int m = 1; m <= NM; m++) {
            cd[m] = dmom[m - 1] * c_invfact[m];
            cn[m] = nmom[m] * c_invfact[m];
        }
        float4 qa = *(const float4*)&sQ[R][g * 8];
        float4 qb = *(const float4*)&sQ[R][g * 8 + 4];
        float qs[8] = {qa.x, qa.y, qa.z, qa.w, qb.x, qb.y, qb.z, qb.w};
        unsigned hiw[4], low[4];
        #pragma unroll
        for (int i = 0; i < 8; i++) {
            float t = qs[i];
            float d = cd[NM], nn = cn[NM];
            #pragma unroll
            for (int m = NM - 1; m >= 0; m--) {
                d = fmaf(d, t, cd[m]);
                nn = fmaf(nn, t, cn[m]);
            }
            float o = silu_(nn * rcpf_(d));
            unsigned short oh = bfhi(o);
            unsigned short olo = bfhi(o - bf2f(oh));
            if (i & 1) { hiw[i >> 1] |= ((unsigned)oh) << 16; low[i >> 1] |= ((unsigned)olo) << 16; }
            else       { hiw[i >> 1] = oh; low[i >> 1] = olo; }
        }
        *(uint4*)&hAhi[R][g * 8] = make_uint4(hiw[0], hiw[1], hiw[2], hiw[3]);
        *(uint4*)&hAlo[R][g * 8] = make_uint4(low[0], low[1], low[2], low[3]);
        __syncthreads();

        // P4: h2 = silu(attn4 @ Wh^T + b_h). K=128, N=64; wave w: 2 tiles.
        short8 Ah[4], Al[4];
        #pragma unroll
        for (int kt = 0; kt < 4; kt++) {
            Ah[kt] = *(const short8*)&hAhi[m16 & 7][kt * 32 + quad * 8];
            Al[kt] = *(const short8*)&hAlo[m16 & 7][kt * 32 + quad * 8];
        }
        #pragma unroll
        for (int t = 0; t < 2; t++) {
            const int n = (w * 2 + t) * 16 + m16;
            short8 bh[4], bl[4];
            if (t == 0) {
                #pragma unroll
                for (int kt = 0; kt < 4; kt++) { bh[kt] = p4bh[kt]; bl[kt] = p4bl[kt]; }
            } else {
                #pragma unroll
                for (int kt = 0; kt < 4; kt++) {
                    bh[kt] = *(const short8*)&whh[n * 128 + kt * 32 + quad * 8];
                    bl[kt] = *(const short8*)&whl[n * 128 + kt * 32 + quad * 8];
                }
            }
            float b = b_h[n];
            f32x4 acc0 = {b, b, b, b};
            f32x4 acc1 = {0.f, 0.f, 0.f, 0.f};
            #pragma unroll
            for (int kt = 0; kt < 4; kt++) {
                if (kt & 1) {
                    acc1 = __builtin_amdgcn_mfma_f32_16x16x32_bf16(Ah[kt], bh[kt], acc1, 0, 0, 0);
                    acc1 = __builtin_amdgcn_mfma_f32_16x16x32_bf16(Ah[kt], bl[kt], acc1, 0, 0, 0);
                    acc1 = __builtin_amdgcn_mfma_f32_16x16x32_bf16(Al[kt], bh[kt], acc1, 0, 0, 0);
                } else {
                    acc0 = __builtin_amdgcn_mfma_f32_16x16x32_bf16(Ah[kt], bh[kt], acc0, 0, 0, 0);
                    acc0 = __builtin_amdgcn_mfma_f32_16x16x32_bf16(Ah[kt], bl[kt], acc0, 0, 0, 0);
                    acc0 = __builtin_amdgcn_mfma_f32_16x16x32_bf16(Al[kt], bh[kt], acc0, 0, 0, 0);
                }
            }
            if (quad < 2) {
                #pragma unroll
                for (int reg = 0; reg < 4; reg++) {
                    int row = quad * 4 + reg;
                    float hv = silu_(acc0[reg] + acc1[reg]);
                    unsigned short hh = bfhi(hv);
                    h2hi[row][n] = hh;
                    h2lo[row][n] = bfhi(hv - bf2f(hh));
                }
            }
        }
    }
    __syncthreads();

    // P5: qkv7 via MFMA bf16x3. M=16 (8 rows dup), K=64, N=192. wave w: 6 tiles.
    {
        const unsigned short* u7 = (const unsigned short*)(ws + 58880);
        short8 Ah[2], Al[2];
        #pragma unroll
        for (int kt = 0; kt < 2; kt++) {
            Ah[kt] = *(const short8*)&h2hi[m16 & 7][kt * 32 + quad * 8];
            Al[kt] = *(const short8*)&h2lo[m16 & 7][kt * 32 + quad * 8];
        }
        #pragma unroll 3
        for (int t = 0; t < 6; t++) {
            const int nt = w * 6 + t;
            const int mat = nt >> 2;           // 0=q,1=k,2=v
            const int n = (nt & 3) * 16 + m16;
            const float* bp = (mat == 0) ? Bq7 : (mat == 1) ? Bk7 : Bv7;
            float b = bp[n];
            f32x4 acc0 = {b, b, b, b};
            f32x4 acc1 = {0.f, 0.f, 0.f, 0.f};
            const unsigned short* Bh = u7 + mat * 8192 + n * 64;
            const unsigned short* Bl = Bh + 4096;
            short8 bh0 = *(const short8*)&Bh[quad * 8];
            short8 bl0 = *(const short8*)&Bl[quad * 8];
            short8 bh1 = *(const short8*)&Bh[32 + quad * 8];
            short8 bl1 = *(const short8*)&Bl[32 + quad * 8];
            acc0 = __builtin_amdgcn_mfma_f32_16x16x32_bf16(Ah[0], bh0, acc0, 0, 0, 0);
            acc1 = __builtin_amdgcn_mfma_f32_16x16x32_bf16(Ah[1], bh1, acc1, 0, 0, 0);
            acc0 = __builtin_amdgcn_mfma_f32_16x16x32_bf16(Ah[0], bl0, acc0, 0, 0, 0);
            acc1 = __builtin_amdgcn_mfma_f32_16x16x32_bf16(Ah[1], bl1, acc1, 0, 0, 0);
            acc0 = __builtin_amdgcn_mfma_f32_16x16x32_bf16(Al[0], bh0, acc0, 0, 0, 0);
            acc1 = __builtin_amdgcn_mfma_f32_16x16x32_bf16(Al[1], bh1, acc1, 0, 0, 0);
            if (quad < 2) {
                #pragma unroll
                for (int reg = 0; reg < 4; reg++) {
                    int row = quad * 4 + reg;
                    float val = silu_(acc0[reg] + acc1[reg]);
                    if (mat == 0)      sQ[row][n] = val;
                    else if (mat == 1) sKVb[row][n][0] = bfrn(val);
                    else               sKVb[row][n][1] = bfrn(val);
                }
            }
        }
    }
    __syncthreads();

    // P6: attention over 64 via Taylor moments; lane: j,i in g*4..g*4+3
    {
        float dmom[NM];
        float nmom[NM + 1];
        #pragma unroll
        for (int m = 0; m < NM; m++) dmom[m] = 0.f;
        #pragma unroll
        for (int m = 0; m <= NM; m++) nmom[m] = 0.f;
        uint4 u0 = *(const uint4*)&sKVb[R][g * 4][0];
        unsigned us[4] = {u0.x, u0.y, u0.z, u0.w};
        #pragma unroll
        for (int jj = 0; jj < 4; jj++) {
            unsigned u = us[jj];
            float kf = __uint_as_float(u << 16);
            float vf = __uint_as_float(u & 0xffff0000u);
            nmom[0] += vf;
            float p = kf;
            dmom[0] += p; nmom[1] = fmaf(vf, p, nmom[1]);
            #pragma unroll
            for (int m = 1; m < NM; m++) {
                p *= kf;
                dmom[m] += p;
                nmom[m + 1] = fmaf(vf, p, nmom[m + 1]);
            }
        }
        #pragma unroll
        for (int m = 0; m < NM; m++) dmom[m] = rsum16(dmom[m]);
        #pragma unroll
        for (int m = 0; m <= NM; m++) nmom[m] = rsum16(nmom[m]);
        float cd[NM + 1], cn[NM + 1];
        cd[0] = 64.f; cn[0] = nmom[0];
        #pragma unroll
        for (int m = 1; m <= NM; m++) {
            cd[m] = dmom[m - 1] * c_invfact[m];
            cn[m] = nmom[m] * c_invfact[m];
        }
        float4 qa = *(const float4*)&sQ[R][g * 4];
        float qs[4] = {qa.x, qa.y, qa.z, qa.w};
        #pragma unroll
        for (int i = 0; i < 4; i++) {
            float t = qs[i];
            float d = cd[NM], nn = cn[NM];
            #pragma unroll
            for (int m = NM - 1; m >= 0; m--) {
                d = fmaf(d, t, cd[m]);
                nn = fmaf(nn, t, cn[m]);
            }
            h3T[w][g * 4 + i][r] = silu_(nn * rcpf_(d));
        }
    }
    // h3T slice is wave-private from here on — no block sync needed.

    // P7: y = silu(attn7 @ Wout^T + b_out), 64 -> 25, split across lane halves
    {
        const int o = l & 31;
        const int half = l >> 5;
        const int oc = (o < 25) ? o : 0;
        float y[RPW];
        float bb = (half == 0) ? b_out[oc] : 0.f;
        #pragma unroll
        for (int rr = 0; rr < RPW; rr++) y[rr] = bb;
        const int in0 = half * 32;
        #pragma unroll 4
        for (int i = 0; i < 32; i++) {
            int in = in0 + i;
            float wv = WoutT[in * 25 + oc];
            float4 xr = *(const float4*)&h3T[w][in][0];
            y[0] = fmaf(xr.x, wv, y[0]);
            y[1] = fmaf(xr.y, wv, y[1]);
            y[2] = fmaf(xr.z, wv, y[2]);
            y[3] = fmaf(xr.w, wv, y[3]);
        }
        #pragma unroll
        for (int rr = 0; rr < RPW; rr++) {
            float full = y[rr] + __shfl_xor(y[rr], 32, 64);
            if (l < 25) sY[w][rr][l] = silu_(full);
        }
    }

    // P8: quadratic epilogue; lanes l < RPW, one row each
    if (l < RPW) {
        const int rr = l;
        float y[25];
        #pragma unroll
        for (int c = 0; c < 25; c++) y[c] = sY[w][rr][c];
        float M11 = 0.f, M12 = 0.f, M21 = 0.f, M22 = 0.f, Mpp = 0.f;
        #pragma unroll
        for (int c = 0; c < 5; c++) {
            M11 = fmaf(y[c], y[c], M11);
            M12 = fmaf(y[5 + c], y[5 + c], M12);
            M21 = fmaf(y[10 + c], y[10 + c], M21);
            M22 = fmaf(y[15 + c], y[15 + c], M22);
            Mpp = fmaf(y[20 + c], y[20 + c], Mpp);
        }
        float quad_ = M11 * (y[0] * y[0] + y[1] * y[1])
                    + (M12 + M21) * (y[0] * y[2] + y[1] * y[3])
                    + M22 * (y[2] * y[2] + y[3] * y[3]);
        out[row0 + rr] = quad_ + Mpp;
    }
}

extern "C" void kernel_launch(void* const* d_in, const int* in_sizes, int n_in,
                              void* d_out, int out_size, void* d_ws, size_t ws_size,
                              hipStream_t stream) {
    const float* x    = (const float*)d_in[0];
    const float* W_in = (const float*)d_in[2];
    const float* b_in = (const float*)d_in[3];
    const float* Aq4  = (const float*)d_in[4];
    const float* Bq4  = (const float*)d_in[5];
    const float* Ak4  = (const float*)d_in[6];
    const float* Bk4  = (const float*)d_in[7];
    const float* Av4  = (const float*)d_in[8];
    const float* Bv4  = (const float*)d_in[9];
    const float* W_h  = (const float*)d_in[10];
    const float* b_h  = (const float*)d_in[11];
    const float* Aq7  = (const float*)d_in[12];
    const float* Bq7  = (const float*)d_in[13];
    const float* Ak7  = (const float*)d_in[14];
    const float* Bk7  = (const float*)d_in[15];
    const float* Av7  = (const float*)d_in[16];
    const float* Bv7  = (const float*)d_in[17];
    const float* Wout = (const float*)d_in[18];
    const float* bout = (const float*)d_in[19];
    float* ws = (float*)d_ws;

    tweights<<<256, 256, 0, stream>>>(W_in, Aq4, Ak4, Av4, W_h, Aq7, Ak7, Av7, Wout, ws);

    const int B = in_sizes[0] / 12;        // 16384
    const int grid = B / RPB;              // 2048
    fused_net<<<grid, 128, 0, stream>>>(x, ws, b_in, Bq4, Bk4, Bv4,
                                        b_h, Bq7, Bk7, Bv7, bout, (float*)d_out);
}

// Round 9
// 151.256 us; speedup vs baseline: 1.0788x; 1.0788x over previous
//
#include <hip/hip_runtime.h>

#define NM 12               // Taylor degree (terms 0..12)

using short8 = __attribute__((ext_vector_type(8))) short;
using f32x4  = __attribute__((ext_vector_type(4))) float;

#define LOG2E 1.4426950408889634f

static __device__ __forceinline__ float ex2(float x) { return __builtin_amdgcn_exp2f(x); }
static __device__ __forceinline__ float rcpf_(float x) { return __builtin_amdgcn_rcpf(x); }
static __device__ __forceinline__ float silu_(float x) {
    return x * rcpf_(1.0f + ex2(-x * LOG2E));
}
static __device__ __forceinline__ unsigned short bfhi(float x) {          // truncate
    return (unsigned short)(__float_as_uint(x) >> 16);
}
static __device__ __forceinline__ unsigned short bfrn(float x) {          // round-nearest
    unsigned u = __float_as_uint(x);
    return (unsigned short)((u + 0x7fffu + ((u >> 16) & 1u)) >> 16);
}
static __device__ __forceinline__ float bf2f(unsigned short h) {
    return __uint_as_float(((unsigned)h) << 16);
}

// ---- DPP 16-lane rotation-sum: VALU pipe, zero LDS traffic ------------------
template <int CTRL>
static __device__ __forceinline__ float dpp_rot(float v) {
    return __uint_as_float(
        __builtin_amdgcn_update_dpp(0u, __float_as_uint(v), CTRL, 0xF, 0xF, true));
}
static __device__ __forceinline__ float rsum16(float v) {
    v += dpp_rot<0x128>(v);   // row_ror:8
    v += dpp_rot<0x124>(v);   // row_ror:4
    v += dpp_rot<0x122>(v);   // row_ror:2
    v += dpp_rot<0x121>(v);   // row_ror:1
    return v;
}

__constant__ float c_invfact[13] = {
    1.f, 1.f, 0.5f, 1.f/6, 1.f/24, 1.f/120, 1.f/720, 1.f/5040, 1.f/40320,
    1.f/362880, 1.f/3628800, 1.f/39916800, 1.f/479001600};

#define MFMA16(A, B, C) __builtin_amdgcn_mfma_f32_16x16x32_bf16((A), (B), (C), 0, 0, 0)

// ---------------- weight prep in d_ws ---------------------------------------
template <int O, int I>
__device__ __forceinline__ void tr(const float* __restrict__ s, float* __restrict__ d,
                                   int t0, int stride) {
    for (int idx = t0; idx < O * I; idx += stride) {
        int o = idx / I, in = idx - o * I;
        d[in * O + o] = s[idx];
    }
}
template <int N>
__device__ __forceinline__ void cvt(const float* __restrict__ s,
                                    unsigned short* __restrict__ hi,
                                    unsigned short* __restrict__ lo,
                                    int t0, int stride) {
    for (int i = t0; i < N; i += stride) {
        float a = s[i];
        unsigned short h = bfhi(a);
        float r = a - bf2f(h);
        hi[i] = h;
        lo[i] = bfhi(r);
    }
}

__global__ void tweights(const float* __restrict__ s0, const float* __restrict__ s1,
                         const float* __restrict__ s2, const float* __restrict__ s3,
                         const float* __restrict__ s4, const float* __restrict__ s5,
                         const float* __restrict__ s6, const float* __restrict__ s7,
                         const float* __restrict__ s8, float* __restrict__ ws) {
    const int stride = gridDim.x * blockDim.x;
    const int t0 = blockIdx.x * blockDim.x + threadIdx.x;
    tr<128, 12>(s0, ws + 0, t0, stride);                       // WinT fp32 [12][128]
    unsigned short* u4 = (unsigned short*)(ws + 1536);
    cvt<128 * 128>(s1, u4 + 0,     u4 + 16384, t0, stride);    // Aq4 hi/lo [o][in]
    cvt<128 * 128>(s2, u4 + 32768, u4 + 49152, t0, stride);    // Ak4
    cvt<128 * 128>(s3, u4 + 65536, u4 + 81920, t0, stride);    // Av4
    unsigned short* wh = (unsigned short*)(ws + 50688);
    cvt<64 * 128>(s4, wh + 0, wh + 8192, t0, stride);          // Wh hi/lo [64][128]
    unsigned short* u7 = (unsigned short*)(ws + 58880);
    cvt<64 * 64>(s5, u7 + 0,     u7 + 4096,  t0, stride);      // Aq7
    cvt<64 * 64>(s6, u7 + 8192,  u7 + 12288, t0, stride);      // Ak7
    cvt<64 * 64>(s7, u7 + 16384, u7 + 20480, t0, stride);      // Av7
    tr<25, 64>(s8, ws + 71168, t0, stride);                    // WoutT fp32 [64][25]
}

// ------- fused per-row network: 32 rows/block, two 16-row groups pipelined ---
__global__ __launch_bounds__(256, 2) void fused_net(
    const float* __restrict__ x, const float* __restrict__ ws,
    const float* __restrict__ b_in,
    const float* __restrict__ Bq4, const float* __restrict__ Bk4, const float* __restrict__ Bv4,
    const float* __restrict__ b_h,
    const float* __restrict__ Bq7, const float* __restrict__ Bk7, const float* __restrict__ Bv7,
    const float* __restrict__ b_out,
    float* __restrict__ out) {
    __shared__ __align__(16) unsigned short hAhi[2][16][136], hAlo[2][16][136];
    __shared__ __align__(16) unsigned short h2hi[2][16][80],  h2lo[2][16][80];
    __shared__ __align__(16) float sQ[2][16][132];
    __shared__ __align__(16) unsigned short sKVb[2][16][132][2];
    __shared__ __align__(16) float h3T[2][4][64][4];
    __shared__ __align__(16) float sXT[2][4][12][4];
    __shared__ __align__(16) float sY[2][4][4][26];

    const int tid = threadIdx.x;
    const int w = tid >> 6;
    const int l = tid & 63;
    const int row0 = blockIdx.x * 32;
    const int m16 = l & 15, quad = l >> 4;
    const int g = l & 15, r = l >> 4;      // attention: 16 lanes per row
    const int R = w * 4 + r;               // group-row this lane reduces/evaluates

    const float* WinT  = ws + 0;      // [12][128] fp32
    const float* WoutT = ws + 71168;  // [64][25]  fp32
    const unsigned short* u4  = (const unsigned short*)(ws + 1536);
    const unsigned short* whh = (const unsigned short*)(ws + 50688);
    const unsigned short* whl = whh + 8192;
    const unsigned short* u7  = (const unsigned short*)(ws + 58880);

    auto stageX = [&](int G) {
        if (l < 48) {
            int rr = l / 12, in = l - rr * 12;
            sXT[G][w][in][rr] = x[(row0 + G * 16 + w * 4 + rr) * 12 + in];
        }
    };

    auto phase1 = [&](int G) {   // h = silu(x @ Win^T + b_in)
        float2 bb = *(const float2*)&b_in[2 * l];
        float a0[4], a1[4];
        #pragma unroll
        for (int rr = 0; rr < 4; rr++) { a0[rr] = bb.x; a1[rr] = bb.y; }
        #pragma unroll
        for (int in = 0; in < 12; in++) {
            float2 wv = *(const float2*)&WinT[in * 128 + 2 * l];
            float4 xr = *(const float4*)&sXT[G][w][in][0];
            a0[0] = fmaf(xr.x, wv.x, a0[0]); a1[0] = fmaf(xr.x, wv.y, a1[0]);
            a0[1] = fmaf(xr.y, wv.x, a0[1]); a1[1] = fmaf(xr.y, wv.y, a1[1]);
            a0[2] = fmaf(xr.z, wv.x, a0[2]); a1[2] = fmaf(xr.z, wv.y, a1[2]);
            a0[3] = fmaf(xr.w, wv.x, a0[3]); a1[3] = fmaf(xr.w, wv.y, a1[3]);
        }
        #pragma unroll
        for (int rr = 0; rr < 4; rr++) {
            float h0 = silu_(a0[rr]), h1 = silu_(a1[rr]);
            unsigned short h0h = bfhi(h0), h1h = bfhi(h1);
            float r0 = h0 - bf2f(h0h), r1 = h1 - bf2f(h1h);
            *(unsigned*)&hAhi[G][w * 4 + rr][2 * l] = (unsigned)h0h | ((unsigned)h1h << 16);
            *(unsigned*)&hAlo[G][w * 4 + rr][2 * l] = (unsigned)bfhi(r0) | ((unsigned)bfhi(r1) << 16);
        }
    };

    auto phase2 = [&](int G) {   // qkv4 MFMA bf16x3: M=16,K=128,N=384; wave: 6 tiles
        short8 Ah[4], Al[4];
        #pragma unroll
        for (int kt = 0; kt < 4; kt++) {
            Ah[kt] = *(const short8*)&hAhi[G][m16][kt * 32 + quad * 8];
            Al[kt] = *(const short8*)&hAlo[G][m16][kt * 32 + quad * 8];
        }
        #pragma unroll
        for (int t = 0; t < 6; t++) {
            const int nt = w * 6 + t;
            const int mat = nt >> 3;           // 0=q,1=k,2=v (wave-uniform)
            const int n = (nt & 7) * 16 + m16;
            const float* bp = (mat == 0) ? Bq4 : (mat == 1) ? Bk4 : Bv4;
            float b = bp[n];
            f32x4 acc0 = {b, b, b, b};
            f32x4 acc1 = {0.f, 0.f, 0.f, 0.f};
            const unsigned short* Bh = u4 + mat * 32768 + n * 128;
            const unsigned short* Bl = Bh + 16384;
            #pragma unroll
            for (int kt = 0; kt < 4; kt++) {
                short8 bh = *(const short8*)&Bh[kt * 32 + quad * 8];
                short8 bl = *(const short8*)&Bl[kt * 32 + quad * 8];
                if (kt & 1) {
                    acc1 = MFMA16(Ah[kt], bh, acc1);
                    acc1 = MFMA16(Ah[kt], bl, acc1);
                    acc1 = MFMA16(Al[kt], bh, acc1);
                } else {
                    acc0 = MFMA16(Ah[kt], bh, acc0);
                    acc0 = MFMA16(Ah[kt], bl, acc0);
                    acc0 = MFMA16(Al[kt], bh, acc0);
                }
            }
            #pragma unroll
            for (int reg = 0; reg < 4; reg++) {
                int row = quad * 4 + reg;
                float val = silu_(acc0[reg] + acc1[reg]);
                if (mat == 0)      sQ[G][row][n] = val;
                else if (mat == 1) sKVb[G][row][n][0] = bfrn(val);
                else               sKVb[G][row][n][1] = bfrn(val);
            }
        }
    };

    auto phase3 = [&](int G) {   // attention over 128 via Taylor moments
        float dmom[NM], nmom[NM + 1];
        #pragma unroll
        for (int m = 0; m < NM; m++) dmom[m] = 0.f;
        #pragma unroll
        for (int m = 0; m <= NM; m++) nmom[m] = 0.f;
        uint4 u0 = *(const uint4*)&sKVb[G][R][g * 8][0];
        uint4 u1 = *(const uint4*)&sKVb[G][R][g * 8 + 4][0];
        unsigned us[8] = {u0.x, u0.y, u0.z, u0.w, u1.x, u1.y, u1.z, u1.w};
        #pragma unroll
        for (int jj = 0; jj < 8; jj++) {
            unsigned u = us[jj];
            float kf = __uint_as_float(u << 16);
            float vf = __uint_as_float(u & 0xffff0000u);
            nmom[0] += vf;
            float p = kf;
            dmom[0] += p; nmom[1] = fmaf(vf, p, nmom[1]);
            #pragma unroll
            for (int m = 1; m < NM; m++) {
                p *= kf;
                dmom[m] += p;
                nmom[m + 1] = fmaf(vf, p, nmom[m + 1]);
            }
        }
        #pragma unroll
        for (int m = 0; m < NM; m++) dmom[m] = rsum16(dmom[m]);
        #pragma unroll
        for (int m = 0; m <= NM; m++) nmom[m] = rsum16(nmom[m]);
        float cd[NM + 1], cn[NM + 1];
        cd[0] = 128.f; cn[0] = nmom[0];
        #pragma unroll
        for (int m = 1; m <= NM; m++) {
            cd[m] = dmom[m - 1] * c_invfact[m];
            cn[m] = nmom[m] * c_invfact[m];
        }
        float4 qa = *(const float4*)&sQ[G][R][g * 8];
        float4 qb = *(const float4*)&sQ[G][R][g * 8 + 4];
        float qs[8] = {qa.x, qa.y, qa.z, qa.w, qb.x, qb.y, qb.z, qb.w};
        unsigned hiw[4], low[4];
        #pragma unroll
        for (int i = 0; i < 8; i++) {
            float t = qs[i];
            float d = cd[NM], nn = cn[NM];
            #pragma unroll
            for (int m = NM - 1; m >= 0; m--) {
                d = fmaf(d, t, cd[m]);
                nn = fmaf(nn, t, cn[m]);
            }
            float o = silu_(nn * rcpf_(d));
            unsigned short oh = bfhi(o);
            unsigned short olo = bfhi(o - bf2f(oh));
            if (i & 1) { hiw[i >> 1] |= ((unsigned)oh) << 16; low[i >> 1] |= ((unsigned)olo) << 16; }
            else       { hiw[i >> 1] = oh; low[i >> 1] = olo; }
        }
        *(uint4*)&hAhi[G][R][g * 8] = make_uint4(hiw[0], hiw[1], hiw[2], hiw[3]);
        *(uint4*)&hAlo[G][R][g * 8] = make_uint4(low[0], low[1], low[2], low[3]);
    };

    auto phase4 = [&](int G) {   // h2 = silu(attn4 @ Wh^T + b_h): K=128,N=64; 1 tile/wave
        short8 Ah[4], Al[4];
        #pragma unroll
        for (int kt = 0; kt < 4; kt++) {
            Ah[kt] = *(const short8*)&hAhi[G][m16][kt * 32 + quad * 8];
            Al[kt] = *(const short8*)&hAlo[G][m16][kt * 32 + quad * 8];
        }
        const int n = w * 16 + m16;
        float b = b_h[n];
        f32x4 acc0 = {b, b, b, b};
        f32x4 acc1 = {0.f, 0.f, 0.f, 0.f};
        #pragma unroll
        for (int kt = 0; kt < 4; kt++) {
            short8 bh = *(const short8*)&whh[n * 128 + kt * 32 + quad * 8];
            short8 bl = *(const short8*)&whl[n * 128 + kt * 32 + quad * 8];
            if (kt & 1) {
                acc1 = MFMA16(Ah[kt], bh, acc1);
                acc1 = MFMA16(Ah[kt], bl, acc1);
                acc1 = MFMA16(Al[kt], bh, acc1);
            } else {
                acc0 = MFMA16(Ah[kt], bh, acc0);
                acc0 = MFMA16(Ah[kt], bl, acc0);
                acc0 = MFMA16(Al[kt], bh, acc0);
            }
        }
        #pragma unroll
        for (int reg = 0; reg < 4; reg++) {
            int row = quad * 4 + reg;
            float hv = silu_(acc0[reg] + acc1[reg]);
            unsigned short hh = bfhi(hv);
            h2hi[G][row][n] = hh;
            h2lo[G][row][n] = bfhi(hv - bf2f(hh));
        }
    };

    auto phase5 = [&](int G) {   // qkv7 MFMA bf16x3: M=16,K=64,N=192; wave: 3 tiles
        short8 Ah[2], Al[2];
        #pragma unroll
        for (int kt = 0; kt < 2; kt++) {
            Ah[kt] = *(const short8*)&h2hi[G][m16][kt * 32 + quad * 8];
            Al[kt] = *(const short8*)&h2lo[G][m16][kt * 32 + quad * 8];
        }
        #pragma unroll
        for (int t = 0; t < 3; t++) {
            const int nt = w * 3 + t;
            const int mat = nt >> 2;           // 0=q,1=k,2=v
            const int n = (nt & 3) * 16 + m16;
            const float* bp = (mat == 0) ? Bq7 : (mat == 1) ? Bk7 : Bv7;
            float b = bp[n];
            f32x4 acc0 = {b, b, b, b};
            f32x4 acc1 = {0.f, 0.f, 0.f, 0.f};
            const unsigned short* Bh = u7 + mat * 8192 + n * 64;
            const unsigned short* Bl = Bh + 4096;
            short8 bh0 = *(const short8*)&Bh[quad * 8];
            short8 bl0 = *(const short8*)&Bl[quad * 8];
            short8 bh1 = *(const short8*)&Bh[32 + quad * 8];
            short8 bl1 = *(const short8*)&Bl[32 + quad * 8];
            acc0 = MFMA16(Ah[0], bh0, acc0);
            acc1 = MFMA16(Ah[1], bh1, acc1);
            acc0 = MFMA16(Ah[0], bl0, acc0);
            acc1 = MFMA16(Ah[1], bl1, acc1);
            acc0 = MFMA16(Al[0], bh0, acc0);
            acc1 = MFMA16(Al[1], bh1, acc1);
            #pragma unroll
            for (int reg = 0; reg < 4; reg++) {
                int row = quad * 4 + reg;
                float val = silu_(acc0[reg] + acc1[reg]);
                if (mat == 0)      sQ[G][row][n] = val;
                else if (mat == 1) sKVb[G][row][n][0] = bfrn(val);
                else               sKVb[G][row][n][1] = bfrn(val);
            }
        }
    };

    auto phase6 = [&](int G) {   // attention over 64 via Taylor moments
        float dmom[NM], nmom[NM + 1];
        #pragma unroll
        for (int m = 0; m < NM; m++) dmom[m] = 0.f;
        #pragma unroll
        for (int m = 0; m <= NM; m++) nmom[m] = 0.f;
        uint4 u0 = *(const uint4*)&sKVb[G][R][g * 4][0];
        unsigned us[4] = {u0.x, u0.y, u0.z, u0.w};
        #pragma unroll
        for (int jj = 0; jj < 4; jj++) {
            unsigned u = us[jj];
            float kf = __uint_as_float(u << 16);
            float vf = __uint_as_float(u & 0xffff0000u);
            nmom[0] += vf;
            float p = kf;
            dmom[0] += p; nmom[1] = fmaf(vf, p, nmom[1]);
            #pragma unroll
            for (int m = 1; m < NM; m++) {
                p *= kf;
                dmom[m] += p;
                nmom[m + 1] = fmaf(vf, p, nmom[m + 1]);
            }
        }
        #pragma unroll
        for (int m = 0; m < NM; m++) dmom[m] = rsum16(dmom[m]);
        #pragma unroll
        for (int m = 0; m <= NM; m++) nmom[m] = rsum16(nmom[m]);
        float cd[NM + 1], cn[NM + 1];
        cd[0] = 64.f; cn[0] = nmom[0];
        #pragma unroll
        for (int m = 1; m <= NM; m++) {
            cd[m] = dmom[m - 1] * c_invfact[m];
            cn[m] = nmom[m] * c_invfact[m];
        }
        float4 qa = *(const float4*)&sQ[G][R][g * 4];
        float qs[4] = {qa.x, qa.y, qa.z, qa.w};
        #pragma unroll
        for (int i = 0; i < 4; i++) {
            float t = qs[i];
            float d = cd[NM], nn = cn[NM];
            #pragma unroll
            for (int m = NM - 1; m >= 0; m--) {
                d = fmaf(d, t, cd[m]);
                nn = fmaf(nn, t, cn[m]);
            }
            h3T[G][w][g * 4 + i][r] = silu_(nn * rcpf_(d));
        }
    };

    auto phase78 = [&](int G) {  // y = silu(attn7 @ Wout^T + b_out) + quadratic epilogue
        {
            const int o = l & 31;
            const int half = l >> 5;
            const int oc = (o < 25) ? o : 0;
            float y[4];
            float bb = (half == 0) ? b_out[oc] : 0.f;
            #pragma unroll
            for (int rr = 0; rr < 4; rr++) y[rr] = bb;
            const int in0 = half * 32;
            #pragma unroll 4
            for (int i = 0; i < 32; i++) {
                int in = in0 + i;
                float wv = WoutT[in * 25 + oc];
                float4 xr = *(const float4*)&h3T[G][w][in][0];
                y[0] = fmaf(xr.x, wv, y[0]);
                y[1] = fmaf(xr.y, wv, y[1]);
                y[2] = fmaf(xr.z, wv, y[2]);
                y[3] = fmaf(xr.w, wv, y[3]);
            }
            #pragma unroll
            for (int rr = 0; rr < 4; rr++) {
                float full = y[rr] + __shfl_xor(y[rr], 32, 64);
                if (l < 25) sY[G][w][rr][l] = silu_(full);
            }
        }
        if (l < 4) {
            const int rr = l;
            float y[25];
            #pragma unroll
            for (int c = 0; c < 25; c++) y[c] = sY[G][w][rr][c];
            float M11 = 0.f, M12 = 0.f, M21 = 0.f, M22 = 0.f, Mpp = 0.f;
            #pragma unroll
            for (int c = 0; c < 5; c++) {
                M11 = fmaf(y[c], y[c], M11);
                M12 = fmaf(y[5 + c], y[5 + c], M12);
                M21 = fmaf(y[10 + c], y[10 + c], M21);
                M22 = fmaf(y[15 + c], y[15 + c], M22);
                Mpp = fmaf(y[20 + c], y[20 + c], Mpp);
            }
            float quad_ = M11 * (y[0] * y[0] + y[1] * y[1])
                        + (M12 + M21) * (y[0] * y[2] + y[1] * y[3])
                        + M22 * (y[2] * y[2] + y[3] * y[3]);
            out[row0 + G * 16 + w * 4 + rr] = quad_ + Mpp;
        }
    };

    // ---- software pipeline: phase_k(A) paired with phase_{k-1}(B) ----
    stageX(0); stageX(1);
    phase1(0);
    __syncthreads();
    phase2(0); phase1(1);
    __syncthreads();
    phase2(1); phase3(0);
    __syncthreads();
    phase4(0); phase3(1);
    __syncthreads();
    phase5(0); phase4(1);
    __syncthreads();
    phase5(1); phase6(0);
    __syncthreads();
    phase78(0); phase6(1);
    phase78(1);            // h3T[1]/sY[1] are wave-private after phase6(1)
}

extern "C" void kernel_launch(void* const* d_in, const int* in_sizes, int n_in,
                              void* d_out, int out_size, void* d_ws, size_t ws_size,
                              hipStream_t stream) {
    const float* x    = (const float*)d_in[0];
    const float* W_in = (const float*)d_in[2];
    const float* b_in = (const float*)d_in[3];
    const float* Aq4  = (const float*)d_in[4];
    const float* Bq4  = (const float*)d_in[5];
    const float* Ak4  = (const float*)d_in[6];
    const float* Bk4  = (const float*)d_in[7];
    const float* Av4  = (const float*)d_in[8];
    const float* Bv4  = (const float*)d_in[9];
    const float* W_h  = (const float*)d_in[10];
    const float* b_h  = (const float*)d_in[11];
    const float* Aq7  = (const float*)d_in[12];
    const float* Bq7  = (const float*)d_in[13];
    const float* Ak7  = (const float*)d_in[14];
    const float* Bk7  = (const float*)d_in[15];
    const float* Av7  = (const float*)d_in[16];
    const float* Bv7  = (const float*)d_in[17];
    const float* Wout = (const float*)d_in[18];
    const float* bout = (const float*)d_in[19];
    float* ws = (float*)d_ws;

    tweights<<<256, 256, 0, stream>>>(W_in, Aq4, Ak4, Av4, W_h, Aq7, Ak7, Av7, Wout, ws);

    const int B = in_sizes[0] / 12;        // 16384
    const int grid = B / 32;               // 512
    fused_net<<<grid, 256, 0, stream>>>(x, ws, b_in, Bq4, Bk4, Bv4,
                                        b_h, Bq7, Bk7, Bv7, bout, (float*)d_out);
}